// Round 3
// baseline (8000.160 us; speedup 1.0000x reference)
//
#include <hip/hip_runtime.h>
#include <cstdint>
#include <cstddef>

// Problem constants (B=8, N=2048, M=256)
#define NB 8
#define NN 2048
#define MM 256

typedef unsigned long long u64;

// monotone float->uint map; canonicalize -0 to +0 so float ties == key ties
__device__ __forceinline__ unsigned mapf(float f) {
  unsigned u = __float_as_uint(f + 0.f);
  return ((int)u >= 0) ? (u ^ 0x80000000u) : ~u;
}
__device__ __forceinline__ u64 shflx_u64(u64 v, int m) {
  unsigned lo = (unsigned)__shfl_xor((int)(unsigned)v, m);
  unsigned hi = (unsigned)__shfl_xor((int)(v >> 32), m);
  return ((u64)hi << 32) | lo;
}

// L1-bypass load (sc0): reads the XCD-shared L2 — coherent among blocks that
// are VERIFIED (via HW_REG_XCC_ID) to sit on the same XCD.
__device__ __forceinline__ u64 load_sc0(const u64* p) {
  u64 v;
  asm volatile("global_load_dwordx2 %0, %1, off sc0\n\ts_waitcnt vmcnt(0)"
               : "=v"(v) : "v"(p) : "memory");
  return v;
}
// Plain store: write-through L1 into the local L2 (fast-path publish).
__device__ __forceinline__ void store_plain(u64* p, u64 v) {
  asm volatile("global_store_dwordx2 %0, %1, off" :: "v"(p), "v"(v) : "memory");
}

// ---------------------------------------------------------------------------
// Phase A: LSTM trajectory + fused Q projection.
//
// 64 linear blocks x 1024 thr. STARTUP ELECTION (the round-3 change):
//  1. Every block reads its physical XCC ID (s_getreg HW_REG_XCC_ID, verified
//     0..7 on MI355X) and publishes it to a 64-word map (memset to 0xFF by
//     the host each launch, so stale placements from prior runs can't leak).
//  2. Every block polls the full map (one word per lane), then computes the
//     IDENTICAL deterministic assignment: each XCD hosting >=8 blocks gets
//     whole batches (fast mode: exchange through the XCD-shared L2 via plain
//     store + sc0 load — architecturally coherent, no guessing); remaining
//     batches are staffed from the spare pool with the proven LLC protocol.
//     Counting: 64 blocks, 8 batches x 8 slots -> spares exactly cover any
//     shortfall, so every batch is always fully staffed; no placement can
//     deadlock. Round-1's failure was latching "fast" from a TIMING probe
//     (first-touch LLC refill looks coherent, then the polled stale L2 line
//     stays resident forever); XCC IDs are ground truth, not timing.
//  3. Fast mode keeps an every-16th LLC safety probe and producers always
//     publish to Hslow too: even a wrong XCC read degrades (bounded), never
//     hangs.
// Exchange payload: tagged u64 (h | (t+1)<<32), one atomic 8B word, exact-tag
// match, double-buffered by parity. Stale cross-run content is a single final
// value (2047/2048) which can never equal the exact tag being awaited before
// fresh writes land (progression argument, unchanged from prior rounds).
// Block (b, j) owns m in [32j,32j+32) -> 128 gate rows; thread holds 32 w_hh
// weights in registers. ONE barrier per step. LDS layouts bank-conflict-free
// (verified: SQ_LDS_BANK_CONFLICT 2.5e7 -> 0).
// ---------------------------------------------------------------------------
__global__ __launch_bounds__(1024) void lstm_kernel(
    const float* __restrict__ z_g, const float* __restrict__ dec,
    const float* __restrict__ h0, const float* __restrict__ w_ih,
    const float* __restrict__ w_hh, const float* __restrict__ b_ih,
    const float* __restrict__ b_hh, const float* __restrict__ Wq,
    const float* __restrict__ bq, float* __restrict__ Qout,
    u64* __restrict__ Hfast, u64* __restrict__ Hslow,
    unsigned* __restrict__ xccmap)
{
  const int flat = blockIdx.x;          // 0..63
  const int tid = threadIdx.x;
  const int w = tid >> 6;
  const int lane = tid & 63;

  // ---- election: publish XCC id, poll full map, compute assignment ----
  unsigned myxcc;
  asm volatile("s_getreg_b32 %0, hwreg(HW_REG_XCC_ID)" : "=s"(myxcc));
  myxcc &= 7u;
  if (tid == 0)
    __hip_atomic_store(&xccmap[flat], myxcc, __ATOMIC_RELAXED,
                       __HIP_MEMORY_SCOPE_AGENT);
  unsigned mv;
  for (;;) {
    mv = __hip_atomic_load(&xccmap[lane], __ATOMIC_RELAXED,
                           __HIP_MEMORY_SCOPE_AGENT);
    if (__all((int)(mv != 0xFFFFFFFFu))) break;
  }
  mv &= 7u;

  u64 bal[8];
  #pragma unroll
  for (int x = 0; x < 8; ++x) bal[x] = __ballot((int)(mv == (unsigned)x));

  const u64 below_me = ((u64)1 << flat) - 1;   // flat<64; flat==63 ok
  int acc8 = 0, my_r = 0, my_nb = 0, my_base = 0;
  #pragma unroll
  for (int x = 0; x < 8; ++x) {
    int nb = __popcll(bal[x]) >> 3;
    const int room = 8 - acc8;
    if (nb > room) nb = room;
    if ((unsigned)x == myxcc) {
      my_r = __popcll(bal[x] & below_me);
      my_nb = nb; my_base = acc8;
    }
    acc8 += nb;
  }

  int b, j, fastmode;
  if (my_r < 8 * my_nb) {                 // fast team on my XCD
    b = my_base + (my_r >> 3);
    j = my_r & 7;
    fastmode = 1;
  } else if (acc8 < 8) {                  // spare pool -> LLC-mode batches
    const u64 below_l = ((u64)1 << lane) - 1;
    u64 balm = bal[0];
    #pragma unroll
    for (int x = 1; x < 8; ++x) balm = (mv == (unsigned)x) ? bal[x] : balm;
    const int rl = __popcll(balm & below_l);
    int acc2 = 0, nb_l = 0;
    #pragma unroll
    for (int x = 0; x < 8; ++x) {
      int nb = __popcll(bal[x]) >> 3;
      const int room = 8 - acc2;
      if (nb > room) nb = room;
      if ((unsigned)x == mv) nb_l = nb;
      acc2 += nb;
    }
    const u64 sm = __ballot((int)(rl >= 8 * nb_l));   // spare blocks
    const int sr = __popcll(sm & below_me);
    b = acc8 + (sr >> 3);
    j = sr & 7;
    fastmode = 0;
    if (b >= 8) return;                   // excess spare (can't happen; guard)
  } else {
    return;                               // excess spare, all batches fast
  }

  const int q = w & 7;           // k-quarter: cols [32q, 32q+32)
  const int rg = w >> 3;         // row-group
  const int lr = rg * 64 + lane; // 0..127 local gate row
  const int g = lr >> 5;         // gate 0..3 (i,f,g,o)
  const int mi = lr & 31;
  const int grow = g * 256 + 32 * j + mi;

  __shared__ __align__(16) float part[2][8][128];   // gate partials [q][lr]
  __shared__ __align__(16) float part2[2][32][33];  // q partials [g*8+q][mi]

  // recurrent weights -> 32 registers (8 float4, constant-indexed)
  float wreg[32];
  {
    const float* wr = w_hh + (size_t)grow * MM + 32 * q;
    #pragma unroll
    for (int i = 0; i < 8; ++i) {
      float4 v = *(const float4*)(wr + 4 * i);
      wreg[4 * i + 0] = v.x; wreg[4 * i + 1] = v.y;
      wreg[4 * i + 2] = v.z; wreg[4 * i + 3] = v.w;
    }
  }
  // Wq slice: row 32j+mi, cols [32q+8g, 32q+8g+8)
  float wqa[8];
  {
    const float* wr = Wq + (size_t)(32 * j + mi) * MM + 32 * q + 8 * g;
    float4 w0 = *(const float4*)(wr);
    float4 w1 = *(const float4*)(wr + 4);
    wqa[0] = w0.x; wqa[1] = w0.y; wqa[2] = w0.z; wqa[3] = w0.w;
    wqa[4] = w1.x; wqa[5] = w1.y; wqa[6] = w1.z; wqa[7] = w1.w;
  }
  const float bqv = (w == 1 && lane < 32) ? bq[32 * j + lane] : 0.f;

  // xb = dec@w_ih.T + b_ih + b_hh partials via part[0]
  {
    float p = 0.f;
    const float* wr = w_ih + (size_t)grow * MM + 32 * q;
    #pragma unroll
    for (int i = 0; i < 8; ++i) {
      float4 wv = *(const float4*)(wr + 4 * i);
      float4 dv = *(const float4*)(dec + 32 * q + 4 * i);
      p += wv.x * dv.x + wv.y * dv.y + wv.z * dv.z + wv.w * dv.w;
    }
    part[0][q][lr] = p;
  }
  __syncthreads();

  // wave 0: xb for its two cell rows (lane, lane+64) -> registers
  float xbA = 0.f, xbB = 0.f, c_my = 0.f;
  if (w == 0) {
    #pragma unroll
    for (int rr = 0; rr < 2; ++rr) {
      const int lr2 = lane + rr * 64;
      const int g2 = lr2 >> 5, mi2 = lr2 & 31;
      const int grow2 = g2 * 256 + 32 * j + mi2;
      float xb = b_ih[grow2] + b_hh[grow2];
      #pragma unroll
      for (int qq = 0; qq < 8; ++qq) xb += part[0][qq][lr2];
      if (rr == 0) xbA = xb; else xbB = xb;
    }
    if (lane < 32) c_my = z_g[b * MM + 32 * j + lane];
  }
  __syncthreads();

  u64* Hf = Hfast + (size_t)b * 512;
  u64* Hs = Hslow + (size_t)b * 512;
  const int hidx = 32 * q + (lane & 31);

  for (int t = 0; t <= NN; ++t) {
    // ---- acquire h^(t) quarter into registers ----
    int hvi;
    if (t == 0) {
      hvi = __float_as_int(h0[hidx]);
    } else if (fastmode) {
      // XCC-verified same-L2 poll (~200cy period) + every-16th LLC safety net
      const int off = ((t & 1) << 8) + hidx;
      u64 v = load_sc0(Hf + off);
      int tries = 0;
      while (!__all((int)((unsigned)(v >> 32) == (unsigned)t))) {
        ++tries;
        v = ((tries & 15) == 15)
                ? __hip_atomic_load(Hs + off, __ATOMIC_RELAXED,
                                    __HIP_MEMORY_SCOPE_AGENT)
                : load_sc0(Hf + off);
      }
      hvi = (int)(unsigned)v;
    } else {
      // LLC-coherent poll (guaranteed-progress backbone, round-2 proven)
      const int off = ((t & 1) << 8) + hidx;
      u64 v = __hip_atomic_load(Hs + off, __ATOMIC_RELAXED,
                                __HIP_MEMORY_SCOPE_AGENT);
      while (!__all((int)((unsigned)(v >> 32) == (unsigned)t))) {
        v = __hip_atomic_load(Hs + off, __ATOMIC_RELAXED,
                              __HIP_MEMORY_SCOPE_AGENT);
      }
      hvi = (int)(unsigned)v;
    }

    // ---- matvec partial: 4 interleaved fma chains over the quarter ----
    {
      float a0 = 0.f, a1 = 0.f, a2 = 0.f, a3 = 0.f;
      #pragma unroll
      for (int k = 0; k < 32; k += 4) {
        a0 = fmaf(__uint_as_float((unsigned)__builtin_amdgcn_readlane(hvi, k + 0)), wreg[k + 0], a0);
        a1 = fmaf(__uint_as_float((unsigned)__builtin_amdgcn_readlane(hvi, k + 1)), wreg[k + 1], a1);
        a2 = fmaf(__uint_as_float((unsigned)__builtin_amdgcn_readlane(hvi, k + 2)), wreg[k + 2], a2);
        a3 = fmaf(__uint_as_float((unsigned)__builtin_amdgcn_readlane(hvi, k + 3)), wreg[k + 3], a3);
      }
      part[t & 1][q][lr] = (a0 + a1) + (a2 + a3);
    }

    // ---- q-projection partial from the same quarter (h^(t)) ----
    {
      float qa = 0.f;
      #pragma unroll
      for (int i = 0; i < 8; ++i) {
        const float hh = __uint_as_float((unsigned)__shfl(hvi, 8 * g + i));
        qa = fmaf(hh, wqa[i], qa);
      }
      if (t > 0) part2[t & 1][g * 8 + q][mi] = qa;
    }
    __syncthreads();   // the ONE barrier per step

    // ---- wave 0: cell update on 64 lanes (2 gate rows each) + publish ----
    if (w == 0 && t < NN) {
      float vA = xbA, vB = xbB;
      #pragma unroll
      for (int qq = 0; qq < 8; ++qq) {
        vA += part[t & 1][qq][lane];
        vB += part[t & 1][qq][lane + 64];
      }
      // lanes<32: vA=i-gate, vB=g-gate; lanes>=32: vA=f-gate, vB=o-gate
      const float s1 = 1.f / (1.f + __expf(-vA));               // sigmoid
      const float e  = __expf(((lane < 32) ? -2.f : -1.f) * vB);
      const float s2 = (lane < 32) ? (2.f / (1.f + e) - 1.f)    // tanh
                                   : (1.f / (1.f + e));         // sigmoid
      const float fo1 = __shfl_xor(s1, 32);   // f (at lanes<32)
      const float fo2 = __shfl_xor(s2, 32);   // o (at lanes<32)
      if (lane < 32) {
        c_my = fo1 * c_my + s1 * s2;
        const float e2 = __expf(-2.f * c_my);
        const float hn = fo2 * (2.f / (1.f + e2) - 1.f);
        const u64 pk = ((u64)(unsigned)(t + 1) << 32) | (u64)__float_as_uint(hn);
        const int so = (((t + 1) & 1) << 8) + 32 * j + lane;
        if (fastmode) store_plain(Hf + so, pk);                  // shared L2
        __hip_atomic_store(Hs + so, pk, __ATOMIC_RELAXED,
                           __HIP_MEMORY_SCOPE_AGENT);            // LLC truth
      }
    }

    // ---- wave 1: reduce q partials -> Qout row t-1 (off critical path) ----
    if (w == 1 && t > 0 && lane < 32) {
      float s = 0.f;
      #pragma unroll
      for (int p = 0; p < 32; ++p) s += part2[t & 1][p][lane];
      Qout[((size_t)b * NN + (t - 1)) * MM + 32 * j + lane] = s + bqv;
    }
  }
}

// ---------------------------------------------------------------------------
// C = A @ B^T (+ col bias). 128x128 tile, 256 threads, 8x8 micro-tile.
// ---------------------------------------------------------------------------
__global__ __launch_bounds__(256) void gemm128(
    const float* __restrict__ A, const float* __restrict__ B,
    float* __restrict__ C, const float* __restrict__ bias,
    int K, int Ncol, long sA, long sB, long sC)
{
  __shared__ __align__(16) float As[32][132];
  __shared__ __align__(16) float Bs[32][132];
  const int tid = threadIdx.x;
  const int tx = tid & 15;
  const int ty = tid >> 4;
  const int row0 = blockIdx.y * 128;
  const int col0 = blockIdx.x * 128;
  const float* Ab = A + (size_t)blockIdx.z * (size_t)sA;
  const float* Bb = B + (size_t)blockIdx.z * (size_t)sB;
  float* Cb = C + (size_t)blockIdx.z * (size_t)sC;

  float acc[8][8];
  #pragma unroll
  for (int i = 0; i < 8; ++i)
    #pragma unroll
    for (int jj = 0; jj < 8; ++jj) acc[i][jj] = 0.f;

  for (int k0 = 0; k0 < K; k0 += 32) {
    #pragma unroll
    for (int it = 0; it < 4; ++it) {
      const int idx = tid + it * 256;
      const int r = idx >> 3;
      const int c4 = (idx & 7) << 2;
      float4 va = *(const float4*)(Ab + (size_t)(row0 + r) * K + k0 + c4);
      float4 vb = *(const float4*)(Bb + (size_t)(col0 + r) * K + k0 + c4);
      As[c4 + 0][r] = va.x; As[c4 + 1][r] = va.y;
      As[c4 + 2][r] = va.z; As[c4 + 3][r] = va.w;
      Bs[c4 + 0][r] = vb.x; Bs[c4 + 1][r] = vb.y;
      Bs[c4 + 2][r] = vb.z; Bs[c4 + 3][r] = vb.w;
    }
    __syncthreads();
    #pragma unroll
    for (int kk = 0; kk < 32; ++kk) {
      float4 a0 = *(const float4*)&As[kk][ty * 4];
      float4 a1 = *(const float4*)&As[kk][64 + ty * 4];
      float4 b0 = *(const float4*)&Bs[kk][tx * 4];
      float4 b1 = *(const float4*)&Bs[kk][64 + tx * 4];
      const float av[8] = {a0.x, a0.y, a0.z, a0.w, a1.x, a1.y, a1.z, a1.w};
      const float bv[8] = {b0.x, b0.y, b0.z, b0.w, b1.x, b1.y, b1.z, b1.w};
      #pragma unroll
      for (int i = 0; i < 8; ++i)
        #pragma unroll
        for (int jj = 0; jj < 8; ++jj)
          acc[i][jj] = fmaf(av[i], bv[jj], acc[i][jj]);
    }
    __syncthreads();
  }

  #pragma unroll
  for (int i = 0; i < 8; ++i) {
    const int r = row0 + ((i < 4) ? (ty * 4 + i) : (64 + ty * 4 + i - 4));
    float* cp = Cb + (size_t)r * Ncol + col0;
    float4 o0, o1;
    float* o0p = &o0.x; float* o1p = &o1.x;
    #pragma unroll
    for (int jj = 0; jj < 4; ++jj) {
      float v0 = acc[i][jj], v1 = acc[i][jj + 4];
      if (bias) {
        v0 += bias[col0 + tx * 4 + jj];
        v1 += bias[col0 + 64 + tx * 4 + jj];
      }
      o0p[jj] = v0; o1p[jj] = v1;
    }
    *(float4*)(cp + tx * 4) = o0;
    *(float4*)(cp + 64 + tx * 4) = o1;
  }
}

// ---------------------------------------------------------------------------
// Phase D: exact greedy masked argmax chain, one block (512 thr) per batch.
// ---------------------------------------------------------------------------
__global__ __launch_bounds__(512) void select_block(
    const float* __restrict__ S, int* __restrict__ sel)
{
  const int b = blockIdx.x;
  const int tid = threadIdx.x;
  const int w = tid >> 6;          // 0..7
  const int lane = tid & 63;
  const float* Sb = S + (size_t)b * NN * NN + 4 * tid;
  int* selb = sel + b * NN;

  __shared__ u64 partial[2][8];

  for (int i = tid; i < NN; i += 512) selb[i] = 0x7fffffff;
  __syncthreads();

  unsigned mybits = 0;                 // used flags for my 4 columns
  const unsigned base = 2047u - 4u * (unsigned)tid;

  auto stepf = [&](float4 v, int t) {
    u64 k0 = (mybits & 1u) ? 0 : (((u64)mapf(v.x) << 32) | (base - 0u));
    u64 k1 = (mybits & 2u) ? 0 : (((u64)mapf(v.y) << 32) | (base - 1u));
    u64 k2 = (mybits & 4u) ? 0 : (((u64)mapf(v.z) << 32) | (base - 2u));
    u64 k3 = (mybits & 8u) ? 0 : (((u64)mapf(v.w) << 32) | (base - 3u));
    u64 k = k0 > k1 ? k0 : k1;
    if (k2 > k) k = k2;
    if (k3 > k) k = k3;
    #pragma unroll
    for (int off = 1; off < 64; off <<= 1) {
      u64 o = shflx_u64(k, off);
      if (o > k) k = o;
    }
    if (lane == 0) partial[t & 1][w] = k;
    __syncthreads();
    u64 pk = partial[t & 1][lane & 7];
    #pragma unroll
    for (int off = 1; off < 8; off <<= 1) {
      u64 o = shflx_u64(pk, off);
      if (o > pk) pk = o;
    }
    const int idx = 2047 - (int)(pk & 0x7ff);
    if ((idx >> 2) == tid) mybits |= 1u << (idx & 3);
    if (tid == 0) selb[idx] = t;
  };

  float4 r0 = *(const float4*)(Sb + (size_t)0 * NN);
  float4 r1 = *(const float4*)(Sb + (size_t)1 * NN);
  float4 r2 = *(const float4*)(Sb + (size_t)2 * NN);
  float4 r3 = *(const float4*)(Sb + (size_t)3 * NN);
  for (int t = 0; t < NN; t += 4) {
    const size_t p4 = (size_t)((t + 4 < NN) ? t + 4 : NN - 1) * NN;
    const size_t p5 = (size_t)((t + 5 < NN) ? t + 5 : NN - 1) * NN;
    const size_t p6 = (size_t)((t + 6 < NN) ? t + 6 : NN - 1) * NN;
    const size_t p7 = (size_t)((t + 7 < NN) ? t + 7 : NN - 1) * NN;
    stepf(r0, t);     r0 = *(const float4*)(Sb + p4);
    stepf(r1, t + 1); r1 = *(const float4*)(Sb + p5);
    stepf(r2, t + 2); r2 = *(const float4*)(Sb + p6);
    stepf(r3, t + 3); r3 = *(const float4*)(Sb + p7);
  }
}

// ---------------------------------------------------------------------------
// Phase E: in-place masked softmax per row. Row t masks n iff sel[n] < t.
// ---------------------------------------------------------------------------
__global__ __launch_bounds__(256) void softmax_kernel(
    float* __restrict__ out, const int* __restrict__ sel)
{
  const int t = blockIdx.x;
  const int b = blockIdx.y;
  const int tid = threadIdx.x;
  float* row = out + ((size_t)b * NN + t) * NN;
  const int* selb = sel + b * NN;
  __shared__ float red[8];

  float v[8];
  int sl[8];
  #pragma unroll
  for (int u = 0; u < 2; ++u) {
    float4 f = *(const float4*)(row + u * 1024 + tid * 4);
    int4 s4 = *(const int4*)(selb + u * 1024 + tid * 4);
    v[u * 4 + 0] = f.x; v[u * 4 + 1] = f.y; v[u * 4 + 2] = f.z; v[u * 4 + 3] = f.w;
    sl[u * 4 + 0] = s4.x; sl[u * 4 + 1] = s4.y; sl[u * 4 + 2] = s4.z; sl[u * 4 + 3] = s4.w;
  }

  float mx = -3.0e38f;
  #pragma unroll
  for (int e = 0; e < 8; ++e)
    if (sl[e] >= t) mx = fmaxf(mx, v[e]);
  #pragma unroll
  for (int off = 1; off < 64; off <<= 1) mx = fmaxf(mx, __shfl_xor(mx, off));
  if ((tid & 63) == 0) red[tid >> 6] = mx;
  __syncthreads();
  mx = fmaxf(fmaxf(red[0], red[1]), fmaxf(red[2], red[3]));

  float e8[8];
  float sum = 0.f;
  #pragma unroll
  for (int e = 0; e < 8; ++e) {
    float ex = (sl[e] >= t) ? __expf(v[e] - mx) : 0.f;
    e8[e] = ex;
    sum += ex;
  }
  #pragma unroll
  for (int off = 1; off < 64; off <<= 1) sum += __shfl_xor(sum, off);
  if ((tid & 63) == 0) red[4 + (tid >> 6)] = sum;
  __syncthreads();
  sum = red[4] + red[5] + red[6] + red[7];
  const float inv = 1.f / sum;

  #pragma unroll
  for (int u = 0; u < 2; ++u) {
    float4 o;
    o.x = e8[u * 4 + 0] * inv; o.y = e8[u * 4 + 1] * inv;
    o.z = e8[u * 4 + 2] * inv; o.w = e8[u * 4 + 3] * inv;
    *(float4*)(row + u * 1024 + tid * 4) = o;
  }
}

// ---------------------------------------------------------------------------
// ws layout (floats): keys[4194304] | Q[4194304] | Hfast(u64 4096) |
//                     Hslow(u64 4096) | sel[16384] | xccmap[64]  ~ 33.7 MB
// ---------------------------------------------------------------------------
extern "C" void kernel_launch(void* const* d_in, const int* in_sizes, int n_in,
                              void* d_out, int out_size, void* d_ws, size_t ws_size,
                              hipStream_t stream)
{
  (void)in_sizes; (void)n_in; (void)out_size; (void)ws_size;
  const float* emb  = (const float*)d_in[0];
  const float* z_g  = (const float*)d_in[1];
  const float* dec  = (const float*)d_in[2];
  const float* h0   = (const float*)d_in[3];
  const float* w_ih = (const float*)d_in[4];
  const float* w_hh = (const float*)d_in[5];
  const float* b_ih = (const float*)d_in[6];
  const float* b_hh = (const float*)d_in[7];
  const float* Wq   = (const float*)d_in[8];
  const float* bq   = (const float*)d_in[9];
  const float* Wk   = (const float*)d_in[10];
  const float* bk   = (const float*)d_in[11];
  float* out = (float*)d_out;
  float* ws  = (float*)d_ws;

  float* keys    = ws;
  float* Q       = ws + 4194304;
  u64*   Hfast   = (u64*)(ws + 8388608);
  u64*   Hslow   = (u64*)(ws + 8396800);
  int*   sel     = (int*)(ws + 8404992);
  unsigned* xccm = (unsigned*)(ws + 8421376);

  // poison the XCC map each launch: placement may change run to run
  hipMemsetAsync(xccm, 0xFF, 64 * sizeof(unsigned), stream);

  lstm_kernel<<<64, 1024, 0, stream>>>(
      z_g, dec, h0, w_ih, w_hh, b_ih, b_hh, Wq, bq, Q, Hfast, Hslow, xccm);

  // keys = emb @ Wk.T + bk  ([16384,256] x [256,256]^T)
  gemm128<<<dim3(MM / 128, (NB * NN) / 128, 1), 256, 0, stream>>>(
      emb, Wk, keys, bk, MM, MM, 0, 0, 0);

  // S[b] = Q[b] @ keys[b].T -> straight into d_out
  gemm128<<<dim3(NN / 128, NN / 128, NB), 256, 0, stream>>>(
      Q, keys, out, nullptr, MM, NN,
      (long)NN * MM, (long)NN * MM, (long)NN * NN);

  select_block<<<NB, 512, 0, stream>>>(out, sel);

  softmax_kernel<<<dim3(NN, NB), 256, 0, stream>>>(out, sel);
}

// Round 4
// 5832.083 us; speedup vs baseline: 1.3718x; 1.3718x over previous
//
#include <hip/hip_runtime.h>
#include <cstdint>
#include <cstddef>

// Problem constants (B=8, N=2048, M=256)
#define NB 8
#define NN 2048
#define MM 256

typedef unsigned long long u64;

// monotone float->uint map; canonicalize -0 to +0 so float ties == key ties
__device__ __forceinline__ unsigned mapf(float f) {
  unsigned u = __float_as_uint(f + 0.f);
  return ((int)u >= 0) ? (u ^ 0x80000000u) : ~u;
}
__device__ __forceinline__ u64 shflx_u64(u64 v, int m) {
  unsigned lo = (unsigned)__shfl_xor((int)(unsigned)v, m);
  unsigned hi = (unsigned)__shfl_xor((int)(v >> 32), m);
  return ((u64)hi << 32) | lo;
}

// ---------------------------------------------------------------------------
// Phase A: LSTM trajectory + fused Q projection — GATE-PARTIAL EXCHANGE.
//
// grid(NB, 8) x 1024 thr. Block (b,q) owns column-slice AND m-slice
// [32q, 32q+32). Per step t (computing h_{t+1} from h_t):
//   1. matvec: thread r (=tid, all 1024 gate rows) computes
//      P_q[r] = sum_{k in slice q} w_hh[r][k] * h_t[k]  — h-slice is LOCAL
//      (in LDS, produced by this block last step), weights in 32 VGPRs.
//   2. publish P_q[r] tagged (t+1) as one relaxed agent-scope u64 to LLC.
//      This happens IMMEDIATELY after the matvec — no barrier, no reduce,
//      no transcendentals on the publish path (vs the old h-exchange which
//      paid matvec+barrier+reduce+transcend before publishing).
//   3. q-projection partial (Wq[:,slice q] . h_t) computed in the RT shadow,
//      stored per-block to PQ (lives in d_out, consumed by qreduce before
//      GEMM2 overwrites it).
//   4. poll: thread (s = tid>>7, idx = tid&127) polls ONE u64: source block
//      s's partial for row(q,idx) = (idx>>5)*256 + 32q + (idx&31). Exact-tag
//      match on (t+1); masked reload (only missing lanes reload).
//   5. reduce 8 partials + xb -> gates -> activations -> cell update ->
//      new h-slice into LDS. The block consumes its own h-slice: the
//      h-redistribution exchange hop of rounds 0-3 is GONE.
// One LLC RT per step (unavoidable), ~400 cy of compute+barriers around it.
// Progress guarantee: every block publishes tag t+1 before polling tag t+1,
// so when all blocks finish step t-1 all step-t polls are satisfiable; no
// circular wait, co-residency trivial (64 blocks, 1 per CU). Exchange medium
// is the LLC relaxed-atomic word — the only protocol that survived rounds
// 0-3 (L2 polling starves the producer's stores even with XCC-verified
// placement; 2x regression twice).
// LDS layouts audited conflict-free (2-way max, free per m136).
// ---------------------------------------------------------------------------
__global__ __launch_bounds__(1024) void lstm_kernel(
    const float* __restrict__ z_g, const float* __restrict__ dec,
    const float* __restrict__ h0, const float* __restrict__ w_ih,
    const float* __restrict__ w_hh, const float* __restrict__ b_ih,
    const float* __restrict__ b_hh, const float* __restrict__ Wq,
    float* __restrict__ PQ, u64* __restrict__ Pbuf)
{
  const int b = blockIdx.x;
  const int q = blockIdx.y;
  const int tid = threadIdx.x;

  __shared__ __align__(16) float hbuf[32];     // this block's h-slice
  __shared__ __align__(16) float pp[8][128];   // gate partials [src][idx]
  __shared__ __align__(16) float act[128];     // activated gates
  __shared__ __align__(16) float qq[4][256];   // q-proj partials [seg][m]

  // producer weights: w_hh[row=tid][32q .. 32q+32) -> 32 registers
  float wreg[32];
  {
    const float* wr = w_hh + (size_t)tid * MM + 32 * q;
    #pragma unroll
    for (int i = 0; i < 8; ++i) {
      float4 v = *(const float4*)(wr + 4 * i);
      wreg[4 * i + 0] = v.x; wreg[4 * i + 1] = v.y;
      wreg[4 * i + 2] = v.z; wreg[4 * i + 3] = v.w;
    }
  }
  // q-projection slice: m8 = tid&255 output row, seg = tid>>8 col-oct
  const int m8 = tid & 255;
  const int seg = tid >> 8;
  float wq8[8];
  {
    const float* wr = Wq + (size_t)m8 * MM + 32 * q + 8 * seg;
    float4 w0 = *(const float4*)(wr);
    float4 w1 = *(const float4*)(wr + 4);
    wq8[0] = w0.x; wq8[1] = w0.y; wq8[2] = w0.z; wq8[3] = w0.w;
    wq8[4] = w1.x; wq8[5] = w1.y; wq8[6] = w1.z; wq8[7] = w1.w;
  }

  // consumer mapping: source s, local row idx, global gate row crow
  const int s = tid >> 7;        // 0..7
  const int idx = tid & 127;     // 0..127 (g*32+m)
  const int crow = ((idx >> 5) << 8) + 32 * q + (idx & 31);

  // xb for rows of slice q via one pp-reduce round
  {
    const float* wr = w_ih + (size_t)crow * MM + 32 * s;
    float p = 0.f;
    #pragma unroll
    for (int i = 0; i < 8; ++i) {
      float4 wv = *(const float4*)(wr + 4 * i);
      float4 dv = *(const float4*)(dec + 32 * s + 4 * i);
      p += wv.x * dv.x + wv.y * dv.y + wv.z * dv.z + wv.w * dv.w;
    }
    pp[s][idx] = p;
  }
  __syncthreads();
  float xb = 0.f, c_my = 0.f;
  if (tid < 128) {
    xb = b_ih[crow] + b_hh[crow];
    #pragma unroll
    for (int ss = 0; ss < 8; ++ss) xb += pp[ss][tid];
  }
  if (tid < 32) {
    c_my = z_g[b * MM + 32 * q + tid];
    hbuf[tid] = h0[32 * q + tid];
  }
  __syncthreads();

  u64* Pb = Pbuf + (size_t)b * 8 * 1024;            // per-batch region
  const size_t parstep = (size_t)NB * 8 * 1024;     // parity stride

  for (int t = 0; t < NN; ++t) {
    const int par = (t + 1) & 1;
    const float4* h4 = (const float4*)hbuf;

    // ---- 1. matvec against LOCAL h-slice (8 uniform b128 reads + 32 fma) --
    float a0 = 0.f, a1 = 0.f, a2 = 0.f, a3 = 0.f;
    #pragma unroll
    for (int i = 0; i < 8; ++i) {
      float4 hv = h4[i];
      a0 = fmaf(hv.x, wreg[4 * i + 0], a0);
      a1 = fmaf(hv.y, wreg[4 * i + 1], a1);
      a2 = fmaf(hv.z, wreg[4 * i + 2], a2);
      a3 = fmaf(hv.w, wreg[4 * i + 3], a3);
    }
    const float psum = (a0 + a1) + (a2 + a3);

    // ---- 2. publish immediately (tag t+1) ----
    const u64 pk = ((u64)(unsigned)(t + 1) << 32) | (u64)__float_as_uint(psum);
    __hip_atomic_store(Pb + par * parstep + (size_t)q * 1024 + tid, pk,
                       __ATOMIC_RELAXED, __HIP_MEMORY_SCOPE_AGENT);

    // ---- issue first poll probe early (overlaps qpart below) ----
    const u64* pa = Pb + par * parstep + (size_t)s * 1024 + crow;
    u64 v = __hip_atomic_load(pa, __ATOMIC_RELAXED, __HIP_MEMORY_SCOPE_AGENT);

    // ---- 3. q-projection partial from h_t (RT shadow work) ----
    {
      float4 hA = h4[2 * seg], hB = h4[2 * seg + 1];
      float qa = wq8[0] * hA.x;
      qa = fmaf(wq8[1], hA.y, qa); qa = fmaf(wq8[2], hA.z, qa);
      qa = fmaf(wq8[3], hA.w, qa); qa = fmaf(wq8[4], hB.x, qa);
      qa = fmaf(wq8[5], hB.y, qa); qa = fmaf(wq8[6], hB.z, qa);
      qa = fmaf(wq8[7], hB.w, qa);
      qq[seg][m8] = qa;
    }

    // ---- 4. poll (masked reload: only missing lanes re-fetch) ----
    {
      bool ok = ((unsigned)(v >> 32) == (unsigned)(t + 1));
      while (!__all((int)ok)) {
        if (!ok) {
          v = __hip_atomic_load(pa, __ATOMIC_RELAXED,
                                __HIP_MEMORY_SCOPE_AGENT);
          ok = ((unsigned)(v >> 32) == (unsigned)(t + 1));
        }
      }
    }
    pp[s][idx] = __uint_as_float((unsigned)v);
    __syncthreads();                                   // bar 1

    // ---- 5a. gate reduce + activations (waves 0-1); qsum store (waves 4-7)
    if (tid < 128) {
      float gsum = xb;
      #pragma unroll
      for (int ss = 0; ss < 8; ++ss) gsum += pp[ss][tid];
      const int g = tid >> 5;
      float a;
      if (g == 2) { const float e = __expf(-2.f * gsum); a = 2.f / (1.f + e) - 1.f; }
      else        { a = 1.f / (1.f + __expf(-gsum)); }
      act[tid] = a;
    } else if (tid >= 256 && tid < 512 && t > 0) {
      const int m2 = tid - 256;
      const float qs = qq[0][m2] + qq[1][m2] + qq[2][m2] + qq[3][m2];
      PQ[(((size_t)b * NN + (t - 1)) * 8 + q) * 256 + m2] = qs;
    }
    __syncthreads();                                   // bar 1b

    // ---- 5b. cell update -> new h-slice ----
    if (tid < 32) {
      const float i_g = act[tid], f_g = act[32 + tid];
      const float g_g = act[64 + tid], o_g = act[96 + tid];
      c_my = f_g * c_my + i_g * g_g;
      const float e2 = __expf(-2.f * c_my);
      hbuf[tid] = o_g * (2.f / (1.f + e2) - 1.f);
    }
    __syncthreads();                                   // bar 2
  }

  // tail: q-projection of h_NN -> Qout row NN-1
  {
    const float4* h4 = (const float4*)hbuf;
    float4 hA = h4[2 * seg], hB = h4[2 * seg + 1];
    float qa = wq8[0] * hA.x;
    qa = fmaf(wq8[1], hA.y, qa); qa = fmaf(wq8[2], hA.z, qa);
    qa = fmaf(wq8[3], hA.w, qa); qa = fmaf(wq8[4], hB.x, qa);
    qa = fmaf(wq8[5], hB.y, qa); qa = fmaf(wq8[6], hB.z, qa);
    qa = fmaf(wq8[7], hB.w, qa);
    qq[seg][m8] = qa;
  }
  __syncthreads();
  if (tid >= 256 && tid < 512) {
    const int m2 = tid - 256;
    const float qs = qq[0][m2] + qq[1][m2] + qq[2][m2] + qq[3][m2];
    PQ[(((size_t)b * NN + (NN - 1)) * 8 + q) * 256 + m2] = qs;
  }
}

// ---------------------------------------------------------------------------
// Q[b][t][m] = sum_s PQ[b][t][s][m] + bq[m]
// ---------------------------------------------------------------------------
__global__ __launch_bounds__(256) void qreduce(
    const float* __restrict__ PQ, const float* __restrict__ bq,
    float* __restrict__ Q)
{
  const int t = blockIdx.x;
  const int b = blockIdx.y;
  const int m = threadIdx.x;
  const float* p = PQ + (((size_t)b * NN + t) * 8) * 256 + m;
  float s = bq[m];
  #pragma unroll
  for (int ss = 0; ss < 8; ++ss) s += p[ss * 256];
  Q[((size_t)b * NN + t) * MM + m] = s;
}

// ---------------------------------------------------------------------------
// C = A @ B^T (+ col bias). 128x128 tile, 256 threads, 8x8 micro-tile.
// ---------------------------------------------------------------------------
__global__ __launch_bounds__(256) void gemm128(
    const float* __restrict__ A, const float* __restrict__ B,
    float* __restrict__ C, const float* __restrict__ bias,
    int K, int Ncol, long sA, long sB, long sC)
{
  __shared__ __align__(16) float As[32][132];
  __shared__ __align__(16) float Bs[32][132];
  const int tid = threadIdx.x;
  const int tx = tid & 15;
  const int ty = tid >> 4;
  const int row0 = blockIdx.y * 128;
  const int col0 = blockIdx.x * 128;
  const float* Ab = A + (size_t)blockIdx.z * (size_t)sA;
  const float* Bb = B + (size_t)blockIdx.z * (size_t)sB;
  float* Cb = C + (size_t)blockIdx.z * (size_t)sC;

  float acc[8][8];
  #pragma unroll
  for (int i = 0; i < 8; ++i)
    #pragma unroll
    for (int jj = 0; jj < 8; ++jj) acc[i][jj] = 0.f;

  for (int k0 = 0; k0 < K; k0 += 32) {
    #pragma unroll
    for (int it = 0; it < 4; ++it) {
      const int idx = tid + it * 256;
      const int r = idx >> 3;
      const int c4 = (idx & 7) << 2;
      float4 va = *(const float4*)(Ab + (size_t)(row0 + r) * K + k0 + c4);
      float4 vb = *(const float4*)(Bb + (size_t)(col0 + r) * K + k0 + c4);
      As[c4 + 0][r] = va.x; As[c4 + 1][r] = va.y;
      As[c4 + 2][r] = va.z; As[c4 + 3][r] = va.w;
      Bs[c4 + 0][r] = vb.x; Bs[c4 + 1][r] = vb.y;
      Bs[c4 + 2][r] = vb.z; Bs[c4 + 3][r] = vb.w;
    }
    __syncthreads();
    #pragma unroll
    for (int kk = 0; kk < 32; ++kk) {
      float4 a0 = *(const float4*)&As[kk][ty * 4];
      float4 a1 = *(const float4*)&As[kk][64 + ty * 4];
      float4 b0 = *(const float4*)&Bs[kk][tx * 4];
      float4 b1 = *(const float4*)&Bs[kk][64 + tx * 4];
      const float av[8] = {a0.x, a0.y, a0.z, a0.w, a1.x, a1.y, a1.z, a1.w};
      const float bv[8] = {b0.x, b0.y, b0.z, b0.w, b1.x, b1.y, b1.z, b1.w};
      #pragma unroll
      for (int i = 0; i < 8; ++i)
        #pragma unroll
        for (int jj = 0; jj < 8; ++jj)
          acc[i][jj] = fmaf(av[i], bv[jj], acc[i][jj]);
    }
    __syncthreads();
  }

  #pragma unroll
  for (int i = 0; i < 8; ++i) {
    const int r = row0 + ((i < 4) ? (ty * 4 + i) : (64 + ty * 4 + i - 4));
    float* cp = Cb + (size_t)r * Ncol + col0;
    float4 o0, o1;
    float* o0p = &o0.x; float* o1p = &o1.x;
    #pragma unroll
    for (int jj = 0; jj < 4; ++jj) {
      float v0 = acc[i][jj], v1 = acc[i][jj + 4];
      if (bias) {
        v0 += bias[col0 + tx * 4 + jj];
        v1 += bias[col0 + 64 + tx * 4 + jj];
      }
      o0p[jj] = v0; o1p[jj] = v1;
    }
    *(float4*)(cp + tx * 4) = o0;
    *(float4*)(cp + 64 + tx * 4) = o1;
  }
}

// ---------------------------------------------------------------------------
// Phase D: exact greedy masked argmax chain, one block (512 thr) per batch.
// ---------------------------------------------------------------------------
__global__ __launch_bounds__(512) void select_block(
    const float* __restrict__ S, int* __restrict__ sel)
{
  const int b = blockIdx.x;
  const int tid = threadIdx.x;
  const int w = tid >> 6;          // 0..7
  const int lane = tid & 63;
  const float* Sb = S + (size_t)b * NN * NN + 4 * tid;
  int* selb = sel + b * NN;

  __shared__ u64 partial[2][8];

  for (int i = tid; i < NN; i += 512) selb[i] = 0x7fffffff;
  __syncthreads();

  unsigned mybits = 0;                 // used flags for my 4 columns
  const unsigned base = 2047u - 4u * (unsigned)tid;

  auto stepf = [&](float4 v, int t) {
    u64 k0 = (mybits & 1u) ? 0 : (((u64)mapf(v.x) << 32) | (base - 0u));
    u64 k1 = (mybits & 2u) ? 0 : (((u64)mapf(v.y) << 32) | (base - 1u));
    u64 k2 = (mybits & 4u) ? 0 : (((u64)mapf(v.z) << 32) | (base - 2u));
    u64 k3 = (mybits & 8u) ? 0 : (((u64)mapf(v.w) << 32) | (base - 3u));
    u64 k = k0 > k1 ? k0 : k1;
    if (k2 > k) k = k2;
    if (k3 > k) k = k3;
    #pragma unroll
    for (int off = 1; off < 64; off <<= 1) {
      u64 o = shflx_u64(k, off);
      if (o > k) k = o;
    }
    if (lane == 0) partial[t & 1][w] = k;
    __syncthreads();
    u64 pk = partial[t & 1][lane & 7];
    #pragma unroll
    for (int off = 1; off < 8; off <<= 1) {
      u64 o = shflx_u64(pk, off);
      if (o > pk) pk = o;
    }
    const int idx = 2047 - (int)(pk & 0x7ff);
    if ((idx >> 2) == tid) mybits |= 1u << (idx & 3);
    if (tid == 0) selb[idx] = t;
  };

  float4 r0 = *(const float4*)(Sb + (size_t)0 * NN);
  float4 r1 = *(const float4*)(Sb + (size_t)1 * NN);
  float4 r2 = *(const float4*)(Sb + (size_t)2 * NN);
  float4 r3 = *(const float4*)(Sb + (size_t)3 * NN);
  for (int t = 0; t < NN; t += 4) {
    const size_t p4 = (size_t)((t + 4 < NN) ? t + 4 : NN - 1) * NN;
    const size_t p5 = (size_t)((t + 5 < NN) ? t + 5 : NN - 1) * NN;
    const size_t p6 = (size_t)((t + 6 < NN) ? t + 6 : NN - 1) * NN;
    const size_t p7 = (size_t)((t + 7 < NN) ? t + 7 : NN - 1) * NN;
    stepf(r0, t);     r0 = *(const float4*)(Sb + p4);
    stepf(r1, t + 1); r1 = *(const float4*)(Sb + p5);
    stepf(r2, t + 2); r2 = *(const float4*)(Sb + p6);
    stepf(r3, t + 3); r3 = *(const float4*)(Sb + p7);
  }
}

// ---------------------------------------------------------------------------
// Phase E: in-place masked softmax per row. Row t masks n iff sel[n] < t.
// ---------------------------------------------------------------------------
__global__ __launch_bounds__(256) void softmax_kernel(
    float* __restrict__ out, const int* __restrict__ sel)
{
  const int t = blockIdx.x;
  const int b = blockIdx.y;
  const int tid = threadIdx.x;
  float* row = out + ((size_t)b * NN + t) * NN;
  const int* selb = sel + b * NN;
  __shared__ float red[8];

  float v[8];
  int sl[8];
  #pragma unroll
  for (int u = 0; u < 2; ++u) {
    float4 f = *(const float4*)(row + u * 1024 + tid * 4);
    int4 s4 = *(const int4*)(selb + u * 1024 + tid * 4);
    v[u * 4 + 0] = f.x; v[u * 4 + 1] = f.y; v[u * 4 + 2] = f.z; v[u * 4 + 3] = f.w;
    sl[u * 4 + 0] = s4.x; sl[u * 4 + 1] = s4.y; sl[u * 4 + 2] = s4.z; sl[u * 4 + 3] = s4.w;
  }

  float mx = -3.0e38f;
  #pragma unroll
  for (int e = 0; e < 8; ++e)
    if (sl[e] >= t) mx = fmaxf(mx, v[e]);
  #pragma unroll
  for (int off = 1; off < 64; off <<= 1) mx = fmaxf(mx, __shfl_xor(mx, off));
  if ((tid & 63) == 0) red[tid >> 6] = mx;
  __syncthreads();
  mx = fmaxf(fmaxf(red[0], red[1]), fmaxf(red[2], red[3]));

  float e8[8];
  float sum = 0.f;
  #pragma unroll
  for (int e = 0; e < 8; ++e) {
    float ex = (sl[e] >= t) ? __expf(v[e] - mx) : 0.f;
    e8[e] = ex;
    sum += ex;
  }
  #pragma unroll
  for (int off = 1; off < 64; off <<= 1) sum += __shfl_xor(sum, off);
  if ((tid & 63) == 0) red[4 + (tid >> 6)] = sum;
  __syncthreads();
  sum = red[4] + red[5] + red[6] + red[7];
  const float inv = 1.f / sum;

  #pragma unroll
  for (int u = 0; u < 2; ++u) {
    float4 o;
    o.x = e8[u * 4 + 0] * inv; o.y = e8[u * 4 + 1] * inv;
    o.z = e8[u * 4 + 2] * inv; o.w = e8[u * 4 + 3] * inv;
    *(float4*)(row + u * 1024 + tid * 4) = o;
  }
}

// ---------------------------------------------------------------------------
// ws layout (floats): keys[4194304] | Q[4194304] | Pbuf(u64 131072 = 1MB) |
//                     sel[16384]   ~ 34 MB
// PQ (the per-block q-projection partials, [B][NN][8][256] f32 = 134.2MB)
// lives in d_out, which is exactly that size and is only written by GEMM2
// AFTER qreduce has consumed PQ.
// ---------------------------------------------------------------------------
extern "C" void kernel_launch(void* const* d_in, const int* in_sizes, int n_in,
                              void* d_out, int out_size, void* d_ws, size_t ws_size,
                              hipStream_t stream)
{
  (void)in_sizes; (void)n_in; (void)out_size; (void)ws_size;
  const float* emb  = (const float*)d_in[0];
  const float* z_g  = (const float*)d_in[1];
  const float* dec  = (const float*)d_in[2];
  const float* h0   = (const float*)d_in[3];
  const float* w_ih = (const float*)d_in[4];
  const float* w_hh = (const float*)d_in[5];
  const float* b_ih = (const float*)d_in[6];
  const float* b_hh = (const float*)d_in[7];
  const float* Wq   = (const float*)d_in[8];
  const float* bq   = (const float*)d_in[9];
  const float* Wk   = (const float*)d_in[10];
  const float* bk   = (const float*)d_in[11];
  float* out = (float*)d_out;
  float* ws  = (float*)d_ws;

  float* keys  = ws;
  float* Q     = ws + 4194304;
  u64*   Pbuf  = (u64*)(ws + 8388608);      // 131072 u64 = 1 MB
  int*   sel   = (int*)(ws + 8650752);
  float* PQ    = out;                       // borrowed until qreduce

  // zero the exchange tags (tag 0 is never awaited; awaited tags are >=1)
  hipMemsetAsync(Pbuf, 0, 131072 * sizeof(u64), stream);

  lstm_kernel<<<dim3(NB, 8), 1024, 0, stream>>>(
      z_g, dec, h0, w_ih, w_hh, b_ih, b_hh, Wq, PQ, Pbuf);

  qreduce<<<dim3(NN, NB), 256, 0, stream>>>(PQ, bq, Q);

  // keys = emb @ Wk.T + bk  ([16384,256] x [256,256]^T)
  gemm128<<<dim3(MM / 128, (NB * NN) / 128, 1), 256, 0, stream>>>(
      emb, Wk, keys, bk, MM, MM, 0, 0, 0);

  // S[b] = Q[b] @ keys[b].T -> straight into d_out (overwrites PQ, already
  // consumed by qreduce)
  gemm128<<<dim3(NN / 128, NN / 128, NB), 256, 0, stream>>>(
      Q, keys, out, nullptr, MM, NN,
      (long)NN * MM, (long)NN * MM, (long)NN * NN);

  select_block<<<NB, 512, 0, stream>>>(out, sel);

  softmax_kernel<<<dim3(NN, NB), 256, 0, stream>>>(out, sel);
}

// Round 5
// 4808.142 us; speedup vs baseline: 1.6639x; 1.2130x over previous
//
#include <hip/hip_runtime.h>
#include <cstdint>
#include <cstddef>

// Problem constants (B=8, N=2048, M=256)
#define NB 8
#define NN 2048
#define MM 256

typedef unsigned long long u64;

// monotone float->uint map; canonicalize -0 to +0 so float ties == key ties
__device__ __forceinline__ unsigned mapf(float f) {
  unsigned u = __float_as_uint(f + 0.f);
  return ((int)u >= 0) ? (u ^ 0x80000000u) : ~u;
}
__device__ __forceinline__ u64 shflx_u64(u64 v, int m) {
  unsigned lo = (unsigned)__shfl_xor((int)(unsigned)v, m);
  unsigned hi = (unsigned)__shfl_xor((int)(v >> 32), m);
  return ((u64)hi << 32) | lo;
}

// ---------------------------------------------------------------------------
// Phase A: LSTM trajectory — h-exchange, intra-wave gate reduction.
//
// grid(NB, 8) x 1024 thr. Block (b,q) owns m-slice [32q,32q+32) -> 128 gate
// rows {g*256+32q+m}. Thread layout: wave w holds rows lr=8w..8w+7; within a
// wave, lane = 8*(lr&7) + c8, where c8 in [0,8) is the 32-col segment
// [32c8, 32c8+32). The 8 partials of a gate row live in 8 ADJACENT lanes ->
// reduced by 3 shfl_xor (masks 1,2,4) — this deletes round-2's LDS partial
// dump + wave0's serial 8x128 reduce + 128-transcendental tail, the ~1500cy
// of compute wrapped around the exchange RT.
//
// Exchange (laws from rounds 0-4): LLC relaxed-atomic words ONLY (L2/sc0
// polling starves the producer even with XCC-verified placement — 2x
// regression twice), and MINIMAL volume (agent atomics write through to HBM
// 1:1; round-4's 512KB/step partial exchange = 1.18GB HBM writes, regressed).
// h-exchange: 256 tagged u64 per batch per step = 16KB/step total.
// Distribution: waves 0-3 poll the 256 words (1 word/lane, exact-tag match,
// masked reload) into LDS hbuf; all waves matvec from hbuf.
//
// Bank-conflict audit: naive per-slot reads would put all 8 c8-groups on the
// same 4 banks (8-way conflict). Fix: c8-rotated slot order — at unroll slot
// j, thread reads float4 index 8*c8 + ((j+c8)&7), and its weight registers
// were loaded pre-rotated to match (rotation at weight-LOAD time: global
// addressing, no runtime register indexing, no scratch). Each slot then hits
// all 32 banks exactly once (8 distinct addresses x 8-lane broadcast).
//
// Q-projection is EVICTED from the loop: owner lanes store h to Hall
// (borrowed d_out); Q = Hall @ Wq^T + bq runs as a gemm128 afterwards.
//
// Progress: block publishes tag t+1 only after consuming tag t, so parity
// overwrite of tag t-1 can't race a lagging consumer (it consumed t-1 before
// publishing t, which preceded any t+1). Tag 0 never awaited; Pbuf zeroed.
// ---------------------------------------------------------------------------
__global__ __launch_bounds__(1024) void lstm_kernel(
    const float* __restrict__ z_g, const float* __restrict__ dec,
    const float* __restrict__ h0, const float* __restrict__ w_ih,
    const float* __restrict__ w_hh, const float* __restrict__ b_ih,
    const float* __restrict__ b_hh, float* __restrict__ Hall,
    u64* __restrict__ Pbuf)
{
  const int b = blockIdx.x;
  const int q = blockIdx.y;
  const int tid = threadIdx.x;
  const int w = tid >> 6;
  const int lane = tid & 63;
  const int rr = lane >> 3;        // row within wave 0..7
  const int c8 = lane & 7;         // col segment 0..7
  const int lr = 8 * w + rr;       // local gate row 0..127
  const int g = lr >> 5;           // gate 0..3 (i,f,g,o) — wave-uniform
  const int m = lr & 31;
  const int grow = g * 256 + 32 * q + m;

  __shared__ __align__(16) float hbuf[256];
  __shared__ __align__(16) float act[128];

  // recurrent weights, pre-rotated by c8 so the matvec LDS reads are
  // conflict-free: wreg slot j holds cols 32*c8 + 4*((j+c8)&7) ..+3
  float wreg[32];
  {
    const float* wr = w_hh + (size_t)grow * MM + 32 * c8;
    #pragma unroll
    for (int jj = 0; jj < 8; ++jj) {
      float4 v = *(const float4*)(wr + 4 * ((jj + c8) & 7));
      wreg[4 * jj + 0] = v.x; wreg[4 * jj + 1] = v.y;
      wreg[4 * jj + 2] = v.z; wreg[4 * jj + 3] = v.w;
    }
  }

  // xb = (dec @ w_ih.T)[grow] + b_ih[grow] + b_hh[grow], via the same
  // 8-lane butterfly (one-time)
  float xb;
  {
    const float* wr = w_ih + (size_t)grow * MM + 32 * c8;
    float p = 0.f;
    #pragma unroll
    for (int i = 0; i < 8; ++i) {
      float4 wv = *(const float4*)(wr + 4 * i);
      float4 dv = *(const float4*)(dec + 32 * c8 + 4 * i);
      p += wv.x * dv.x + wv.y * dv.y + wv.z * dv.z + wv.w * dv.w;
    }
    p += __shfl_xor(p, 1); p += __shfl_xor(p, 2); p += __shfl_xor(p, 4);
    xb = p + b_ih[grow] + b_hh[grow];
  }

  float c_my = 0.f;
  if (tid < 32) c_my = z_g[b * MM + 32 * q + tid];
  if (tid < 256) hbuf[tid] = h0[tid];

  u64* Pb = Pbuf + (size_t)b * 512;
  float* Hb = Hall + (size_t)b * NN * MM + 32 * q;

  for (int tt = 0; tt < NN; ++tt) {
    // ---- poll h^(tt) into hbuf (waves 0-3; 1 word/lane; exact tag) ----
    if (tt > 0 && w < 4) {
      const int widx = (w << 6) + lane;
      const u64* pa = Pb + ((tt & 1) << 8) + widx;
      u64 v = __hip_atomic_load(pa, __ATOMIC_RELAXED,
                                __HIP_MEMORY_SCOPE_AGENT);
      bool ok = ((unsigned)(v >> 32) == (unsigned)tt);
      while (!__all((int)ok)) {
        if (!ok) {
          v = __hip_atomic_load(pa, __ATOMIC_RELAXED,
                                __HIP_MEMORY_SCOPE_AGENT);
          ok = ((unsigned)(v >> 32) == (unsigned)tt);
        }
      }
      hbuf[widx] = __uint_as_float((unsigned)v);
    }
    __syncthreads();                                  // BAR A

    // ---- matvec over this thread's 32-col segment (rotated, no conflicts)
    float a0 = 0.f, a1 = 0.f, a2 = 0.f, a3 = 0.f;
    const float4* h4 = (const float4*)hbuf;
    #pragma unroll
    for (int jj = 0; jj < 8; ++jj) {
      float4 hv = h4[8 * c8 + ((jj + c8) & 7)];
      a0 = fmaf(hv.x, wreg[4 * jj + 0], a0);
      a1 = fmaf(hv.y, wreg[4 * jj + 1], a1);
      a2 = fmaf(hv.z, wreg[4 * jj + 2], a2);
      a3 = fmaf(hv.w, wreg[4 * jj + 3], a3);
    }
    float s = (a0 + a1) + (a2 + a3);
    // 8-lane butterfly: every lane gets its row's full dot product
    s += __shfl_xor(s, 1); s += __shfl_xor(s, 2); s += __shfl_xor(s, 4);
    const float gsum = s + xb;

    // activation (redundant x8 lanes; branch is wave-uniform: g = w>>2)
    float a;
    if ((w >> 2) == 2) { const float e = __expf(-2.f * gsum); a = 2.f / (1.f + e) - 1.f; }
    else               { a = 1.f / (1.f + __expf(-gsum)); }
    if (c8 == 0) act[lr] = a;
    __syncthreads();                                  // BAR B

    // ---- cell update + publish (32 owner lanes of wave 0) ----
    if (tid < 32) {
      const float i_g = act[tid], f_g = act[32 + tid];
      const float g_g = act[64 + tid], o_g = act[96 + tid];
      c_my = f_g * c_my + i_g * g_g;
      const float e2 = __expf(-2.f * c_my);
      const float hn = o_g * (2.f / (1.f + e2) - 1.f);
      const u64 pk = ((u64)(unsigned)(tt + 1) << 32) | (u64)__float_as_uint(hn);
      __hip_atomic_store(Pb + (((tt + 1) & 1) << 8) + 32 * q + tid, pk,
                         __ATOMIC_RELAXED, __HIP_MEMORY_SCOPE_AGENT);
      Hb[(size_t)tt * MM + tid] = hn;    // trajectory for the Q gemm
    }
    // no barrier here: next iteration's poll writes hbuf (readers are past
    // BAR B), act readers (wave 0) finish before joining BAR A.
  }
}

// ---------------------------------------------------------------------------
// C = A @ B^T (+ col bias). 128x128 tile, 256 threads, 8x8 micro-tile.
// ---------------------------------------------------------------------------
__global__ __launch_bounds__(256) void gemm128(
    const float* __restrict__ A, const float* __restrict__ B,
    float* __restrict__ C, const float* __restrict__ bias,
    int K, int Ncol, long sA, long sB, long sC)
{
  __shared__ __align__(16) float As[32][132];
  __shared__ __align__(16) float Bs[32][132];
  const int tid = threadIdx.x;
  const int tx = tid & 15;
  const int ty = tid >> 4;
  const int row0 = blockIdx.y * 128;
  const int col0 = blockIdx.x * 128;
  const float* Ab = A + (size_t)blockIdx.z * (size_t)sA;
  const float* Bb = B + (size_t)blockIdx.z * (size_t)sB;
  float* Cb = C + (size_t)blockIdx.z * (size_t)sC;

  float acc[8][8];
  #pragma unroll
  for (int i = 0; i < 8; ++i)
    #pragma unroll
    for (int jj = 0; jj < 8; ++jj) acc[i][jj] = 0.f;

  for (int k0 = 0; k0 < K; k0 += 32) {
    #pragma unroll
    for (int it = 0; it < 4; ++it) {
      const int idx = tid + it * 256;
      const int r = idx >> 3;
      const int c4 = (idx & 7) << 2;
      float4 va = *(const float4*)(Ab + (size_t)(row0 + r) * K + k0 + c4);
      float4 vb = *(const float4*)(Bb + (size_t)(col0 + r) * K + k0 + c4);
      As[c4 + 0][r] = va.x; As[c4 + 1][r] = va.y;
      As[c4 + 2][r] = va.z; As[c4 + 3][r] = va.w;
      Bs[c4 + 0][r] = vb.x; Bs[c4 + 1][r] = vb.y;
      Bs[c4 + 2][r] = vb.z; Bs[c4 + 3][r] = vb.w;
    }
    __syncthreads();
    #pragma unroll
    for (int kk = 0; kk < 32; ++kk) {
      float4 a0 = *(const float4*)&As[kk][ty * 4];
      float4 a1 = *(const float4*)&As[kk][64 + ty * 4];
      float4 b0 = *(const float4*)&Bs[kk][tx * 4];
      float4 b1 = *(const float4*)&Bs[kk][64 + tx * 4];
      const float av[8] = {a0.x, a0.y, a0.z, a0.w, a1.x, a1.y, a1.z, a1.w};
      const float bv[8] = {b0.x, b0.y, b0.z, b0.w, b1.x, b1.y, b1.z, b1.w};
      #pragma unroll
      for (int i = 0; i < 8; ++i)
        #pragma unroll
        for (int jj = 0; jj < 8; ++jj)
          acc[i][jj] = fmaf(av[i], bv[jj], acc[i][jj]);
    }
    __syncthreads();
  }

  #pragma unroll
  for (int i = 0; i < 8; ++i) {
    const int r = row0 + ((i < 4) ? (ty * 4 + i) : (64 + ty * 4 + i - 4));
    float* cp = Cb + (size_t)r * Ncol + col0;
    float4 o0, o1;
    float* o0p = &o0.x; float* o1p = &o1.x;
    #pragma unroll
    for (int jj = 0; jj < 4; ++jj) {
      float v0 = acc[i][jj], v1 = acc[i][jj + 4];
      if (bias) {
        v0 += bias[col0 + tx * 4 + jj];
        v1 += bias[col0 + 64 + tx * 4 + jj];
      }
      o0p[jj] = v0; o1p[jj] = v1;
    }
    *(float4*)(cp + tx * 4) = o0;
    *(float4*)(cp + 64 + tx * 4) = o1;
  }
}

// ---------------------------------------------------------------------------
// Phase D: exact greedy masked argmax chain, one block (512 thr) per batch.
// ---------------------------------------------------------------------------
__global__ __launch_bounds__(512) void select_block(
    const float* __restrict__ S, int* __restrict__ sel)
{
  const int b = blockIdx.x;
  const int tid = threadIdx.x;
  const int w = tid >> 6;          // 0..7
  const int lane = tid & 63;
  const float* Sb = S + (size_t)b * NN * NN + 4 * tid;
  int* selb = sel + b * NN;

  __shared__ u64 partial[2][8];

  for (int i = tid; i < NN; i += 512) selb[i] = 0x7fffffff;
  __syncthreads();

  unsigned mybits = 0;                 // used flags for my 4 columns
  const unsigned base = 2047u - 4u * (unsigned)tid;

  auto stepf = [&](float4 v, int t) {
    u64 k0 = (mybits & 1u) ? 0 : (((u64)mapf(v.x) << 32) | (base - 0u));
    u64 k1 = (mybits & 2u) ? 0 : (((u64)mapf(v.y) << 32) | (base - 1u));
    u64 k2 = (mybits & 4u) ? 0 : (((u64)mapf(v.z) << 32) | (base - 2u));
    u64 k3 = (mybits & 8u) ? 0 : (((u64)mapf(v.w) << 32) | (base - 3u));
    u64 k = k0 > k1 ? k0 : k1;
    if (k2 > k) k = k2;
    if (k3 > k) k = k3;
    #pragma unroll
    for (int off = 1; off < 64; off <<= 1) {
      u64 o = shflx_u64(k, off);
      if (o > k) k = o;
    }
    if (lane == 0) partial[t & 1][w] = k;
    __syncthreads();
    u64 pk = partial[t & 1][lane & 7];
    #pragma unroll
    for (int off = 1; off < 8; off <<= 1) {
      u64 o = shflx_u64(pk, off);
      if (o > pk) pk = o;
    }
    const int idx = 2047 - (int)(pk & 0x7ff);
    if ((idx >> 2) == tid) mybits |= 1u << (idx & 3);
    if (tid == 0) selb[idx] = t;
  };

  float4 r0 = *(const float4*)(Sb + (size_t)0 * NN);
  float4 r1 = *(const float4*)(Sb + (size_t)1 * NN);
  float4 r2 = *(const float4*)(Sb + (size_t)2 * NN);
  float4 r3 = *(const float4*)(Sb + (size_t)3 * NN);
  for (int t = 0; t < NN; t += 4) {
    const size_t p4 = (size_t)((t + 4 < NN) ? t + 4 : NN - 1) * NN;
    const size_t p5 = (size_t)((t + 5 < NN) ? t + 5 : NN - 1) * NN;
    const size_t p6 = (size_t)((t + 6 < NN) ? t + 6 : NN - 1) * NN;
    const size_t p7 = (size_t)((t + 7 < NN) ? t + 7 : NN - 1) * NN;
    stepf(r0, t);     r0 = *(const float4*)(Sb + p4);
    stepf(r1, t + 1); r1 = *(const float4*)(Sb + p5);
    stepf(r2, t + 2); r2 = *(const float4*)(Sb + p6);
    stepf(r3, t + 3); r3 = *(const float4*)(Sb + p7);
  }
}

// ---------------------------------------------------------------------------
// Phase E: in-place masked softmax per row. Row t masks n iff sel[n] < t.
// ---------------------------------------------------------------------------
__global__ __launch_bounds__(256) void softmax_kernel(
    float* __restrict__ out, const int* __restrict__ sel)
{
  const int t = blockIdx.x;
  const int b = blockIdx.y;
  const int tid = threadIdx.x;
  float* row = out + ((size_t)b * NN + t) * NN;
  const int* selb = sel + b * NN;
  __shared__ float red[8];

  float v[8];
  int sl[8];
  #pragma unroll
  for (int u = 0; u < 2; ++u) {
    float4 f = *(const float4*)(row + u * 1024 + tid * 4);
    int4 s4 = *(const int4*)(selb + u * 1024 + tid * 4);
    v[u * 4 + 0] = f.x; v[u * 4 + 1] = f.y; v[u * 4 + 2] = f.z; v[u * 4 + 3] = f.w;
    sl[u * 4 + 0] = s4.x; sl[u * 4 + 1] = s4.y; sl[u * 4 + 2] = s4.z; sl[u * 4 + 3] = s4.w;
  }

  float mx = -3.0e38f;
  #pragma unroll
  for (int e = 0; e < 8; ++e)
    if (sl[e] >= t) mx = fmaxf(mx, v[e]);
  #pragma unroll
  for (int off = 1; off < 64; off <<= 1) mx = fmaxf(mx, __shfl_xor(mx, off));
  if ((tid & 63) == 0) red[tid >> 6] = mx;
  __syncthreads();
  mx = fmaxf(fmaxf(red[0], red[1]), fmaxf(red[2], red[3]));

  float e8[8];
  float sum = 0.f;
  #pragma unroll
  for (int e = 0; e < 8; ++e) {
    float ex = (sl[e] >= t) ? __expf(v[e] - mx) : 0.f;
    e8[e] = ex;
    sum += ex;
  }
  #pragma unroll
  for (int off = 1; off < 64; off <<= 1) sum += __shfl_xor(sum, off);
  if ((tid & 63) == 0) red[4 + (tid >> 6)] = sum;
  __syncthreads();
  sum = red[4] + red[5] + red[6] + red[7];
  const float inv = 1.f / sum;

  #pragma unroll
  for (int u = 0; u < 2; ++u) {
    float4 o;
    o.x = e8[u * 4 + 0] * inv; o.y = e8[u * 4 + 1] * inv;
    o.z = e8[u * 4 + 2] * inv; o.w = e8[u * 4 + 3] * inv;
    *(float4*)(row + u * 1024 + tid * 4) = o;
  }
}

// ---------------------------------------------------------------------------
// ws layout (floats): keys[4194304] | Q[4194304] | Pbuf(u64 4096 = 32KB) |
//                     sel[16384]   ~ 33.7 MB
// Hall (h trajectory, [B][NN][256] f32 = 16.8MB) borrows d_out (134MB),
// consumed by the Q gemm before gemm2 overwrites it.
// ---------------------------------------------------------------------------
extern "C" void kernel_launch(void* const* d_in, const int* in_sizes, int n_in,
                              void* d_out, int out_size, void* d_ws, size_t ws_size,
                              hipStream_t stream)
{
  (void)in_sizes; (void)n_in; (void)out_size; (void)ws_size;
  const float* emb  = (const float*)d_in[0];
  const float* z_g  = (const float*)d_in[1];
  const float* dec  = (const float*)d_in[2];
  const float* h0   = (const float*)d_in[3];
  const float* w_ih = (const float*)d_in[4];
  const float* w_hh = (const float*)d_in[5];
  const float* b_ih = (const float*)d_in[6];
  const float* b_hh = (const float*)d_in[7];
  const float* Wq   = (const float*)d_in[8];
  const float* bq   = (const float*)d_in[9];
  const float* Wk   = (const float*)d_in[10];
  const float* bk   = (const float*)d_in[11];
  float* out = (float*)d_out;
  float* ws  = (float*)d_ws;

  float* keys  = ws;
  float* Q     = ws + 4194304;
  u64*   Pbuf  = (u64*)(ws + 8388608);    // 4096 u64 = 32 KB
  int*   sel   = (int*)(ws + 8396800);
  float* Hall  = out;                     // borrowed until the Q gemm

  // zero exchange tags (tag 0 never awaited; awaited tags >= 1)
  hipMemsetAsync(Pbuf, 0, 4096 * sizeof(u64), stream);

  lstm_kernel<<<dim3(NB, 8), 1024, 0, stream>>>(
      z_g, dec, h0, w_ih, w_hh, b_ih, b_hh, Hall, Pbuf);

  // Q = Hall @ Wq.T + bq  ([16384,256] x [256,256]^T)
  gemm128<<<dim3(MM / 128, (NB * NN) / 128, 1), 256, 0, stream>>>(
      Hall, Wq, Q, bq, MM, MM, 0, 0, 0);

  // keys = emb @ Wk.T + bk
  gemm128<<<dim3(MM / 128, (NB * NN) / 128, 1), 256, 0, stream>>>(
      emb, Wk, keys, bk, MM, MM, 0, 0, 0);

  // S[b] = Q[b] @ keys[b].T -> d_out (overwrites Hall, already consumed)
  gemm128<<<dim3(NN / 128, NN / 128, NB), 256, 0, stream>>>(
      Q, keys, out, nullptr, MM, NN,
      (long)NN * MM, (long)NN * MM, (long)NN * NN);

  select_block<<<NB, 512, 0, stream>>>(out, sel);

  softmax_kernel<<<dim3(NN, NB), 256, 0, stream>>>(out, sel);
}